// Round 6
// baseline (318.733 us; speedup 1.0000x reference)
//
#include <hip/hip_runtime.h>
#include <math.h>

#define B_TOK 8192
#define H_DIM 7168
#define E_NUM 256
#define NKS   4
#define KSL   (H_DIM / NKS)    // 1792
#define BK    32
#define NSTEP (KSL / BK)       // 56 (even)
#define BM    64
#define NMT   (B_TOK / BM)     // 128
#define FLAG_CAP 512
#define TAU   2e-6

typedef _Float16 f16;
typedef __attribute__((ext_vector_type(8))) _Float16 f16x8;
typedef __attribute__((ext_vector_type(4))) float    f32x4;

typedef __attribute__((address_space(1))) const void gvoid_t;
typedef __attribute__((address_space(3))) void       lvoid_t;

__device__ inline void gload_lds16(const void* g, void* s) {
    __builtin_amdgcn_global_load_lds((gvoid_t*)g, (lvoid_t*)s, 16, 0, 0);
}

#define WAITVM(N) do { asm volatile("s_waitcnt vmcnt(" #N ")" ::: "memory"); \
                       __builtin_amdgcn_sched_barrier(0); } while (0)

// ---------------------------------------------------------------------------
// Shared routing math (fp64, verified) + decision margins.
// ---------------------------------------------------------------------------
__device__ __forceinline__ void route_token(
    const double* lv, const double* bj, int l, int hf, int t,
    float* __restrict__ out, double* ming_adj, double* ming_grp)
{
    double m = fmax(fmax(lv[0], lv[1]), fmax(lv[2], lv[3]));
    #pragma unroll
    for (int d = 1; d < 64; d <<= 1) m = fmax(m, __shfl_xor(m, d, 64));
    double sc[4], zs = 0.0;
    #pragma unroll
    for (int q = 0; q < 4; ++q) { sc[q] = exp(lv[q] - m); zs += sc[q]; }
    #pragma unroll
    for (int d = 1; d < 64; d <<= 1) zs += __shfl_xor(zs, d, 64);
    double swb[4];
    #pragma unroll
    for (int q = 0; q < 4; ++q) { sc[q] /= zs; swb[q] = sc[q] + bj[q]; }

    double gsq[4];
    #pragma unroll
    for (int q = 0; q < 4; ++q) {
        double a = swb[q], b = -INFINITY;
        #pragma unroll
        for (int d = 1; d <= 16; d <<= 1) {
            double oa = __shfl_xor(a, d, 64), ob = __shfl_xor(b, d, 64);
            double na = fmax(a, oa);
            double nb = fmax(fmin(a, oa), fmax(b, ob));
            a = na; b = nb;
        }
        gsq[q] = a + b;
    }
    double gsv[8];
    #pragma unroll
    for (int q = 0; q < 4; ++q) {
        gsv[2 * q]     = __shfl(gsq[q], 0, 64);
        gsv[2 * q + 1] = __shfl(gsq[q], 32, 64);
    }

    unsigned selmask = 0; double g4 = 0.0, g5 = 0.0;
    #pragma unroll
    for (int k = 0; k < 5; ++k) {
        double best = -INFINITY; int bg = 0;
        #pragma unroll
        for (int g = 0; g < 8; ++g)
            if (gsv[g] > best) { best = gsv[g]; bg = g; }
        if (k < 4) { selmask |= 1u << bg; g4 = best; } else g5 = best;
        #pragma unroll
        for (int g = 0; g < 8; ++g) if (g == bg) gsv[g] = -INFINITY;
    }
    *ming_grp = g4 - g5;

    double mk[4];
    #pragma unroll
    for (int q = 0; q < 4; ++q)
        mk[q] = ((selmask >> (2 * q + hf)) & 1u) ? swb[q] : -INFINITY;

    double wk[8]; int ek[8]; double wsum = 0.0;
    double prev = 0.0, ming = 1e300;
    #pragma unroll
    for (int k = 0; k < 9; ++k) {
        double vbest = mk[0]; int ebest = l;
        #pragma unroll
        for (int q = 1; q < 4; ++q)
            if (mk[q] > vbest) { vbest = mk[q]; ebest = l + 64 * q; }
        #pragma unroll
        for (int d = 1; d < 64; d <<= 1) {
            double ov = __shfl_xor(vbest, d, 64);
            int    oe = __shfl_xor(ebest, d, 64);
            if (ov > vbest || (ov == vbest && oe < ebest)) { vbest = ov; ebest = oe; }
        }
        if (k > 0) ming = fmin(ming, prev - vbest);
        prev = vbest;
        if (k < 8) {
            const int ol = ebest & 63, oq = ebest >> 6;
            if (l == ol) {
                #pragma unroll
                for (int q = 0; q < 4; ++q) if (q == oq) mk[q] = -INFINITY;
            }
            double cand = (oq == 0) ? sc[0] : (oq == 1) ? sc[1] : (oq == 2) ? sc[2] : sc[3];
            double sv = __shfl(cand, ol, 64);
            wk[k] = sv; ek[k] = ebest; wsum += sv;
        }
    }
    *ming_adj = ming;

    if (l == 0) {
        const double inv = 1.0 / wsum;
        #pragma unroll
        for (int k = 0; k < 8; ++k) {
            out[(size_t)t * 8 + k] = (float)((wk[k] * inv + 1e-20) * 2.5);
            out[(size_t)B_TOK * 8 + (size_t)t * 8 + k] = (float)ek[k];
        }
    }
}

// ---------------------------------------------------------------------------
// Kernel 1: pack W into MFMA-B-fragment-ordered f16 hi/lo; reset flag counter.
// frag global index fg = kf*32 + nf*2 + h; lane l elem j:
// W[kf*32 + (l>>4)*8 + j][nf*16 + (l&15)]; f16 offset = fg*512 + l*8 + j.
// ---------------------------------------------------------------------------
__global__ void convert_w_kernel(const float* __restrict__ W,
                                 f16* __restrict__ wpk,
                                 unsigned* __restrict__ flags) {
    if (blockIdx.x == 0 && threadIdx.x == 0) flags[0] = 0;
    int g = blockIdx.x * 256 + threadIdx.x;
    int n = g & 255, k = g >> 8;
    float v = W[(size_t)k * E_NUM + n];
    f16 hi = (f16)v;
    f16 lo = (f16)(v - (float)hi);
    int kf = k >> 5, tq = (k >> 3) & 3, j = k & 7;
    int nf = n >> 4, l = tq * 16 + (n & 15);
    size_t off = ((size_t)(kf * 32 + nf * 2)) * 512 + (size_t)l * 8 + j;
    wpk[off]       = hi;   // h = 0
    wpk[off + 512] = lo;   // h = 1
}

// ---------------------------------------------------------------------------
// Kernel 2: split-K GEMM. B: global_load_lds double-buffer (32 KB x2),
// counted vmcnt(4), ONE barrier per K-step. A: registers, convert-then-reload.
// BM=64, 8 waves of 32x64, grid 512 -> 2 blocks/CU, 4 waves/SIMD.
// ---------------------------------------------------------------------------
__device__ __forceinline__ void stage_B(const f16* __restrict__ wb, int kf,
                                        char* bbuf, int wid, int l) {
    #pragma unroll
    for (int i = 0; i < 4; ++i) {
        int fi = wid * 4 + i;
        const f16* src = wb + ((size_t)kf * 32 + fi) * 512 + (size_t)l * 8;
        gload_lds16(src, bbuf + fi * 1024);
    }
}

__device__ __forceinline__ void load_A(const float* const (&xb)[2], int t,
                                       float4 (&raw)[2][2]) {
    #pragma unroll
    for (int mf = 0; mf < 2; ++mf) {
        raw[mf][0] = *reinterpret_cast<const float4*>(xb[mf] + (size_t)t * BK);
        raw[mf][1] = *reinterpret_cast<const float4*>(xb[mf] + (size_t)t * BK + 4);
    }
}

__device__ __forceinline__ void conv_A(const float4 (&raw)[2][2],
                                       f16x8 (&ah)[2], f16x8 (&al)[2]) {
    #pragma unroll
    for (int mf = 0; mf < 2; ++mf) {
        float fv[8] = {raw[mf][0].x, raw[mf][0].y, raw[mf][0].z, raw[mf][0].w,
                       raw[mf][1].x, raw[mf][1].y, raw[mf][1].z, raw[mf][1].w};
        #pragma unroll
        for (int j = 0; j < 8; ++j) {
            f16 hh = (f16)fv[j];
            ah[mf][j] = hh;
            al[mf][j] = (f16)(fv[j] - (float)hh);
        }
    }
}

__device__ __forceinline__ void mfma_step(const char* bbuf, int wc, int l,
                                          const f16x8 (&ah)[2], const f16x8 (&al)[2],
                                          f32x4 (&acc)[2][4]) {
    f16x8 b[4][2];
    #pragma unroll
    for (int ni = 0; ni < 4; ++ni)
        #pragma unroll
        for (int h = 0; h < 2; ++h)
            b[ni][h] = *reinterpret_cast<const f16x8*>(
                bbuf + ((wc * 4 + ni) * 2 + h) * 1024 + l * 16);
    __builtin_amdgcn_s_setprio(1);
    #pragma unroll
    for (int mf = 0; mf < 2; ++mf)
        #pragma unroll
        for (int ni = 0; ni < 4; ++ni) {
            acc[mf][ni] = __builtin_amdgcn_mfma_f32_16x16x32_f16(ah[mf], b[ni][0], acc[mf][ni], 0, 0, 0);
            acc[mf][ni] = __builtin_amdgcn_mfma_f32_16x16x32_f16(ah[mf], b[ni][1], acc[mf][ni], 0, 0, 0);
            acc[mf][ni] = __builtin_amdgcn_mfma_f32_16x16x32_f16(al[mf], b[ni][0], acc[mf][ni], 0, 0, 0);
        }
    __builtin_amdgcn_s_setprio(0);
}

__global__ __launch_bounds__(512, 4)
void gemm_kernel(const float* __restrict__ x,
                 const f16* __restrict__ wpk,
                 float* __restrict__ partial) {
    __shared__ __align__(16) char lds[2][32768];   // 64 KiB -> 2 blocks/CU

    const int tid = threadIdx.x;
    const int l   = tid & 63;
    const int wid = tid >> 6;
    // XCD-chunked swizzle: 512 blocks, 64 consecutive logical blocks per XCD.
    const int bid = blockIdx.x;
    const int swz = (bid & 7) * 64 + (bid >> 3);
    const int ks  = swz >> 7;       // 0..3
    const int mt  = swz & 127;      // 0..127
    const int wr  = wid >> 2;       // 0..1
    const int wc  = wid & 3;        // 0..3

    const float* xb[2];
    #pragma unroll
    for (int mf = 0; mf < 2; ++mf) {
        int row = mt * BM + wr * 32 + mf * 16 + (l & 15);
        xb[mf] = x + (size_t)row * H_DIM + ks * KSL + (l >> 4) * 8;
    }
    const f16* wb = wpk + (size_t)(ks * NSTEP) * 32 * 512;

    f32x4 acc[2][4];
    #pragma unroll
    for (int mi = 0; mi < 2; ++mi)
        #pragma unroll
        for (int ni = 0; ni < 4; ++ni) acc[mi][ni] = (f32x4)0.0f;

    float4 rawE[2][2], rawO[2][2];
    f16x8  ah[2], al[2];

    // prologue: queue = [B(0):4, A(0):4, A(1):4]
    stage_B(wb, 0, lds[0], wid, l);
    load_A(xb, 0, rawE);
    load_A(xb, 1, rawO);

    for (int t = 0; t < NSTEP; t += 2) {
        // ---- even tile t: compute lds[0]; stage B(t+1)->lds[1]; A(t+2)->rawE
        if (t < NSTEP - 1) { WAITVM(4); } else { WAITVM(0); }
        __builtin_amdgcn_s_barrier();
        if (t + 1 < NSTEP) stage_B(wb, t + 1, lds[1], wid, l);
        conv_A(rawE, ah, al);                    // rawE free after this
        if (t + 2 < NSTEP) load_A(xb, t + 2, rawE);
        mfma_step(lds[0], wc, l, ah, al, acc);

        // ---- odd tile t+1: compute lds[1]; stage B(t+2)->lds[0]; A(t+3)->rawO
        if (t + 1 < NSTEP) {
            if (t + 1 < NSTEP - 1) { WAITVM(4); } else { WAITVM(0); }
            __builtin_amdgcn_s_barrier();
            if (t + 2 < NSTEP) stage_B(wb, t + 2, lds[0], wid, l);
            conv_A(rawO, ah, al);
            if (t + 3 < NSTEP) load_A(xb, t + 3, rawO);
            mfma_step(lds[1], wc, l, ah, al, acc);
        }
    }

    float* pbase = partial + ((size_t)ks * B_TOK + (size_t)mt * BM) * E_NUM;
    #pragma unroll
    for (int mi = 0; mi < 2; ++mi)
        #pragma unroll
        for (int ni = 0; ni < 4; ++ni)
            #pragma unroll
            for (int r = 0; r < 4; ++r) {
                int rr = wr * 32 + mi * 16 + (l >> 4) * 4 + r;
                int cc = wc * 64 + ni * 16 + (l & 15);
                pbase[(size_t)rr * E_NUM + cc] = acc[mi][ni][r];
            }
}

// ---------------------------------------------------------------------------
// Kernel 3: fast routing + margin flags.
// ---------------------------------------------------------------------------
__global__ __launch_bounds__(512, 1)
void routing_kernel(const float* __restrict__ partial,
                    const float* __restrict__ bias,
                    float* __restrict__ out,
                    unsigned* __restrict__ flags) {
    const int tid  = threadIdx.x;
    const int l    = tid & 63;
    const int wv   = tid >> 6;
    const int tok0 = blockIdx.x * 32;

    double bj[4];
    #pragma unroll
    for (int q = 0; q < 4; ++q) bj[q] = (double)bias[l + 64 * q];
    const int hf = l >> 5;

    for (int i = 0; i < 4; ++i) {
        const int t = tok0 + wv * 4 + i;
        double lv[4];
        #pragma unroll
        for (int q = 0; q < 4; ++q) {
            double s = 0.0;
            #pragma unroll
            for (int ksl = 0; ksl < NKS; ++ksl)
                s += (double)partial[((size_t)ksl * B_TOK + t) * E_NUM + l + 64 * q];
            lv[q] = s;
        }
        double ma, mg;
        route_token(lv, bj, l, hf, t, out, &ma, &mg);
        if (l == 0 && (ma < TAU || mg < TAU)) {
            unsigned idx = atomicAdd(&flags[0], 1u);
            if (idx < FLAG_CAP) flags[1 + idx] = (unsigned)t;
        }
    }
}

// ---------------------------------------------------------------------------
// Kernel 4: exact fp64 partial dots for flagged tokens.
// ---------------------------------------------------------------------------
__global__ __launch_bounds__(256)
void recompute_dot_kernel(const float* __restrict__ x,
                          const float* __restrict__ W,
                          const unsigned* __restrict__ flags,
                          double* __restrict__ dpart) {
    __shared__ float xs[896];
    unsigned count = flags[0]; if (count > FLAG_CAP) count = FLAG_CAP;
    unsigned nj = count * 8;
    for (unsigned j = blockIdx.x; j < nj; j += gridDim.x) {
        unsigned li = j >> 3, sl = j & 7;
        int t = (int)flags[1 + li];
        const float* xb = x + (size_t)t * H_DIM + sl * 896;
        for (int i = threadIdx.x; i < 224; i += 256)
            *reinterpret_cast<float4*>(&xs[i * 4]) =
                *reinterpret_cast<const float4*>(xb + i * 4);
        __syncthreads();
        const float* wp = W + (size_t)(sl * 896) * E_NUM + threadIdx.x;
        double acc = 0.0;
        #pragma unroll 8
        for (int k = 0; k < 896; ++k)
            acc += (double)xs[k] * (double)wp[(size_t)k * E_NUM];
        dpart[((size_t)li * 8 + sl) * E_NUM + threadIdx.x] = acc;
        __syncthreads();
    }
}

// ---------------------------------------------------------------------------
// Kernel 5: exact routing for flagged tokens (overwrites out).
// ---------------------------------------------------------------------------
__global__ __launch_bounds__(64)
void recompute_route_kernel(const double* __restrict__ dpart,
                            const float* __restrict__ bias,
                            const unsigned* __restrict__ flags,
                            float* __restrict__ out) {
    const int l = threadIdx.x;
    unsigned count = flags[0]; if (count > FLAG_CAP) count = FLAG_CAP;
    double bj[4];
    #pragma unroll
    for (int q = 0; q < 4; ++q) bj[q] = (double)bias[l + 64 * q];
    const int hf = l >> 5;
    for (unsigned li = blockIdx.x; li < count; li += gridDim.x) {
        int t = (int)flags[1 + li];
        double lv[4];
        #pragma unroll
        for (int q = 0; q < 4; ++q) {
            double s = 0.0;
            #pragma unroll
            for (int sl = 0; sl < 8; ++sl)
                s += dpart[((size_t)li * 8 + sl) * E_NUM + l + 64 * q];
            lv[q] = s;
        }
        double ma, mg;
        route_token(lv, bj, l, hf, t, out, &ma, &mg);
    }
}

// ---------------------------------------------------------------------------
// Fallback (round-1 verified fp64 kernel).
// ---------------------------------------------------------------------------
#define TM 32
#define HB 64
#define FNST (H_DIM / HB)

__global__ __launch_bounds__(512, 1)
void moe_gate_fallback(const float* __restrict__ x,
                       const float* __restrict__ W,
                       const float* __restrict__ bias,
                       float* __restrict__ out) {
    __shared__ double xs[TM][HB];
    const int tid  = threadIdx.x;
    const int l    = tid & 63;
    const int wv   = tid >> 6;
    const int tok0 = blockIdx.x * TM;
    const int tl = tid >> 4;
    const int ho = (tid & 15) * 4;

    double acc[4][4];
    #pragma unroll
    for (int i = 0; i < 4; ++i)
        #pragma unroll
        for (int q = 0; q < 4; ++q) acc[i][q] = 0.0;

    const float* xrow = x + (size_t)(tok0 + tl) * H_DIM + ho;
    float4 v = *reinterpret_cast<const float4*>(xrow);

    for (int s = 0; s < FNST; ++s) {
        __syncthreads();
        xs[tl][ho + 0] = (double)v.x;
        xs[tl][ho + 1] = (double)v.y;
        xs[tl][ho + 2] = (double)v.z;
        xs[tl][ho + 3] = (double)v.w;
        __syncthreads();
        const int sn = (s + 1 < FNST) ? s + 1 : s;
        v = *reinterpret_cast<const float4*>(xrow + (size_t)sn * HB);
        const float* wh = W + (size_t)s * HB * E_NUM + l;
        #pragma unroll 4
        for (int h = 0; h < HB; h += 2) {
            float wf0[4], wf1[4];
            #pragma unroll
            for (int q = 0; q < 4; ++q) {
                wf0[q] = wh[(size_t)h       * E_NUM + q * 64];
                wf1[q] = wh[(size_t)(h + 1) * E_NUM + q * 64];
            }
            #pragma unroll
            for (int i = 0; i < 4; ++i) {
                const double2 xv = *reinterpret_cast<const double2*>(&xs[wv * 4 + i][h]);
                #pragma unroll
                for (int q = 0; q < 4; ++q) {
                    acc[i][q] = fma((double)wf0[q], xv.x, acc[i][q]);
                    acc[i][q] = fma((double)wf1[q], xv.y, acc[i][q]);
                }
            }
        }
    }

    double bj[4];
    #pragma unroll
    for (int q = 0; q < 4; ++q) bj[q] = (double)bias[l + 64 * q];
    const int hf = l >> 5;

    for (int i = 0; i < 4; ++i) {
        const int t = tok0 + wv * 4 + i;
        double lv[4];
        #pragma unroll
        for (int q = 0; q < 4; ++q) lv[q] = acc[i][q];
        double ma, mg;
        route_token(lv, bj, l, hf, t, out, &ma, &mg);
    }
}

// ---------------------------------------------------------------------------
extern "C" void kernel_launch(void* const* d_in, const int* in_sizes, int n_in,
                              void* d_out, int out_size, void* d_ws, size_t ws_size,
                              hipStream_t stream) {
    const float* x    = (const float*)d_in[0];
    const float* W    = (const float*)d_in[1];
    const float* bias = (const float*)d_in[2];
    float* out = (float*)d_out;

    const size_t flag_off = 7864320;                  // after 7 MB wpk
    const size_t part_off = 8u * 1024 * 1024;
    const size_t need     = part_off + (size_t)NKS * B_TOK * E_NUM * 4;

    if (ws_size >= need) {
        f16*      wpk     = (f16*)d_ws;
        unsigned* flags   = (unsigned*)((char*)d_ws + flag_off);
        float*    partial = (float*)((char*)d_ws + part_off);
        double*   dpart   = (double*)((char*)d_ws + part_off);   // reused after routing

        convert_w_kernel<<<(H_DIM * E_NUM) / 256, 256, 0, stream>>>(W, wpk, flags);
        gemm_kernel<<<NMT * NKS, 512, 0, stream>>>(x, wpk, partial);
        routing_kernel<<<B_TOK / 32, 512, 0, stream>>>(partial, bias, out, flags);
        recompute_dot_kernel<<<1024, 256, 0, stream>>>(x, W, flags, dpart);
        recompute_route_kernel<<<64, 64, 0, stream>>>(dpart, bias, flags, out);
    } else {
        moe_gate_fallback<<<B_TOK / 32, 512, 0, stream>>>(x, W, bias, out);
    }
}

// Round 7
// 295.915 us; speedup vs baseline: 1.0771x; 1.0771x over previous
//
#include <hip/hip_runtime.h>
#include <math.h>

#define B_TOK 8192
#define H_DIM 7168
#define E_NUM 256
#define NKS   4
#define KSL   (H_DIM / NKS)    // 1792
#define BK    32
#define NSTEP (KSL / BK)       // 56 (even)
#define BM    128
#define NMT   (B_TOK / BM)     // 64
#define FLAG_CAP 512
#define TAU   2e-6

typedef _Float16 f16;
typedef __attribute__((ext_vector_type(8))) _Float16 f16x8;
typedef __attribute__((ext_vector_type(4))) float    f32x4;

typedef __attribute__((address_space(1))) const void gvoid_t;
typedef __attribute__((address_space(3))) void       lvoid_t;

__device__ inline void gload_lds16(const void* g, void* s) {
    __builtin_amdgcn_global_load_lds((gvoid_t*)g, (lvoid_t*)s, 16, 0, 0);
}

#define WAITVM(N) do { asm volatile("s_waitcnt vmcnt(" #N ")" ::: "memory"); \
                       __builtin_amdgcn_sched_barrier(0); } while (0)
#define WAITLGKM0() do { asm volatile("s_waitcnt lgkmcnt(0)" ::: "memory"); \
                       __builtin_amdgcn_sched_barrier(0); } while (0)

// ---------------------------------------------------------------------------
// Shared routing math (fp64, verified) + decision margins.
// ---------------------------------------------------------------------------
__device__ __forceinline__ void route_token(
    const double* lv, const double* bj, int l, int hf, int t,
    float* __restrict__ out, double* ming_adj, double* ming_grp)
{
    double m = fmax(fmax(lv[0], lv[1]), fmax(lv[2], lv[3]));
    #pragma unroll
    for (int d = 1; d < 64; d <<= 1) m = fmax(m, __shfl_xor(m, d, 64));
    double sc[4], zs = 0.0;
    #pragma unroll
    for (int q = 0; q < 4; ++q) { sc[q] = exp(lv[q] - m); zs += sc[q]; }
    #pragma unroll
    for (int d = 1; d < 64; d <<= 1) zs += __shfl_xor(zs, d, 64);
    double swb[4];
    #pragma unroll
    for (int q = 0; q < 4; ++q) { sc[q] /= zs; swb[q] = sc[q] + bj[q]; }

    double gsq[4];
    #pragma unroll
    for (int q = 0; q < 4; ++q) {
        double a = swb[q], b = -INFINITY;
        #pragma unroll
        for (int d = 1; d <= 16; d <<= 1) {
            double oa = __shfl_xor(a, d, 64), ob = __shfl_xor(b, d, 64);
            double na = fmax(a, oa);
            double nb = fmax(fmin(a, oa), fmax(b, ob));
            a = na; b = nb;
        }
        gsq[q] = a + b;
    }
    double gsv[8];
    #pragma unroll
    for (int q = 0; q < 4; ++q) {
        gsv[2 * q]     = __shfl(gsq[q], 0, 64);
        gsv[2 * q + 1] = __shfl(gsq[q], 32, 64);
    }

    unsigned selmask = 0; double g4 = 0.0, g5 = 0.0;
    #pragma unroll
    for (int k = 0; k < 5; ++k) {
        double best = -INFINITY; int bg = 0;
        #pragma unroll
        for (int g = 0; g < 8; ++g)
            if (gsv[g] > best) { best = gsv[g]; bg = g; }
        if (k < 4) { selmask |= 1u << bg; g4 = best; } else g5 = best;
        #pragma unroll
        for (int g = 0; g < 8; ++g) if (g == bg) gsv[g] = -INFINITY;
    }
    *ming_grp = g4 - g5;

    double mk[4];
    #pragma unroll
    for (int q = 0; q < 4; ++q)
        mk[q] = ((selmask >> (2 * q + hf)) & 1u) ? swb[q] : -INFINITY;

    double wk[8]; int ek[8]; double wsum = 0.0;
    double prev = 0.0, ming = 1e300;
    #pragma unroll
    for (int k = 0; k < 9; ++k) {
        double vbest = mk[0]; int ebest = l;
        #pragma unroll
        for (int q = 1; q < 4; ++q)
            if (mk[q] > vbest) { vbest = mk[q]; ebest = l + 64 * q; }
        #pragma unroll
        for (int d = 1; d < 64; d <<= 1) {
            double ov = __shfl_xor(vbest, d, 64);
            int    oe = __shfl_xor(ebest, d, 64);
            if (ov > vbest || (ov == vbest && oe < ebest)) { vbest = ov; ebest = oe; }
        }
        if (k > 0) ming = fmin(ming, prev - vbest);
        prev = vbest;
        if (k < 8) {
            const int ol = ebest & 63, oq = ebest >> 6;
            if (l == ol) {
                #pragma unroll
                for (int q = 0; q < 4; ++q) if (q == oq) mk[q] = -INFINITY;
            }
            double cand = (oq == 0) ? sc[0] : (oq == 1) ? sc[1] : (oq == 2) ? sc[2] : sc[3];
            double sv = __shfl(cand, ol, 64);
            wk[k] = sv; ek[k] = ebest; wsum += sv;
        }
    }
    *ming_adj = ming;

    if (l == 0) {
        const double inv = 1.0 / wsum;
        #pragma unroll
        for (int k = 0; k < 8; ++k) {
            out[(size_t)t * 8 + k] = (float)((wk[k] * inv + 1e-20) * 2.5);
            out[(size_t)B_TOK * 8 + (size_t)t * 8 + k] = (float)ek[k];
        }
    }
}

// ---------------------------------------------------------------------------
// Kernel 1: pack W into MFMA-B-fragment-ordered f16 hi/lo; reset flag counter.
// frag fg = kf*32 + nf*2 + h; lane l elem j: W[kf*32+(l>>4)*8+j][nf*16+(l&15)]
// ---------------------------------------------------------------------------
__global__ void convert_w_kernel(const float* __restrict__ W,
                                 f16* __restrict__ wpk,
                                 unsigned* __restrict__ flags) {
    if (blockIdx.x == 0 && threadIdx.x == 0) flags[0] = 0;
    int g = blockIdx.x * 256 + threadIdx.x;
    int n = g & 255, k = g >> 8;
    float v = W[(size_t)k * E_NUM + n];
    f16 hi = (f16)v;
    f16 lo = (f16)(v - (float)hi);
    int kf = k >> 5, tq = (k >> 3) & 3, j = k & 7;
    int nf = n >> 4, l = tq * 16 + (n & 15);
    size_t off = ((size_t)(kf * 32 + nf * 2)) * 512 + (size_t)l * 8 + j;
    wpk[off]       = hi;   // h = 0
    wpk[off + 512] = lo;   // h = 1
}

// ---------------------------------------------------------------------------
// GEMM helpers (all static indexing — rule #20)
// ---------------------------------------------------------------------------
__device__ __forceinline__ f16x8 ldsB(const char* b, int fi, int l) {
    return *reinterpret_cast<const f16x8*>(b + fi * 1024 + l * 16);
}

template<int I0>
__device__ __forceinline__ void stage2(const f16* __restrict__ wb, int kf,
                                       char* bbuf, int wid, int l) {
    #pragma unroll
    for (int i = I0; i < I0 + 2; ++i) {
        int fi = wid * 4 + i;
        gload_lds16(wb + ((size_t)kf * 32 + fi) * 512 + (size_t)l * 8,
                    bbuf + fi * 1024);
    }
}

template<int MF0>
__device__ __forceinline__ void loadA2(const float* const (&xb)[4], int t,
                                       float4 (&raw)[4][2]) {
    #pragma unroll
    for (int mf = MF0; mf < MF0 + 2; ++mf) {
        raw[mf][0] = *reinterpret_cast<const float4*>(xb[mf] + (size_t)t * BK);
        raw[mf][1] = *reinterpret_cast<const float4*>(xb[mf] + (size_t)t * BK + 4);
    }
}

template<int MF0>
__device__ __forceinline__ void conv2(const float4 (&raw)[4][2],
                                      f16x8 (&ah)[4], f16x8 (&al)[4]) {
    #pragma unroll
    for (int mf = MF0; mf < MF0 + 2; ++mf) {
        float fv[8] = {raw[mf][0].x, raw[mf][0].y, raw[mf][0].z, raw[mf][0].w,
                       raw[mf][1].x, raw[mf][1].y, raw[mf][1].z, raw[mf][1].w};
        #pragma unroll
        for (int j = 0; j < 8; ++j) {
            f16 hh = (f16)fv[j];
            ah[mf][j] = hh;
            al[mf][j] = (f16)(fv[j] - (float)hh);
        }
    }
}

template<int NI>
__device__ __forceinline__ void mfma_quad(const f16x8 (&ah)[4], const f16x8 (&al)[4],
                                          f16x8 bh, f16x8 bl, f32x4 (&acc)[4][4]) {
    // product-major order: dependent MFMAs separated by 4 independents
    #pragma unroll
    for (int mf = 0; mf < 4; ++mf)
        acc[mf][NI] = __builtin_amdgcn_mfma_f32_16x16x32_f16(ah[mf], bh, acc[mf][NI], 0, 0, 0);
    #pragma unroll
    for (int mf = 0; mf < 4; ++mf)
        acc[mf][NI] = __builtin_amdgcn_mfma_f32_16x16x32_f16(ah[mf], bl, acc[mf][NI], 0, 0, 0);
    #pragma unroll
    for (int mf = 0; mf < 4; ++mf)
        acc[mf][NI] = __builtin_amdgcn_mfma_f32_16x16x32_f16(al[mf], bh, acc[mf][NI], 0, 0, 0);
}

#define MFMA_PHASE(NI)                                   \
    do {                                                 \
        __builtin_amdgcn_s_barrier();                    \
        WAITLGKM0();                                     \
        __builtin_amdgcn_s_setprio(1);                   \
        mfma_quad<NI>(ahc, alc, bh, bl, acc);            \
        __builtin_amdgcn_s_setprio(0);                   \
    } while (0)

// One K-step (kf = 32), 4 phases. All vm-waits are vmcnt(8) by FIFO account:
// per kf issues: P0 Ba(t+1):2, P1 Bb(t+1):2, P2 Aa(t+2):4, P3 Ab(t+2):4.
__device__ __forceinline__ void kf_step(
    int tS, int tA,
    const char* bcur, char* bnxt, const f16* __restrict__ wb,
    int wid, int l, int wc,
    const float* const (&xb)[4], float4 (&raw)[4][2],
    const f16x8 (&ahc)[4], const f16x8 (&alc)[4],
    f16x8 (&ahn)[4], f16x8 (&aln)[4],
    f32x4 (&acc)[4][4])
{
    const int nfb = wc * 8;
    f16x8 bh, bl;

    // ---- P0: read b0(t); stage Ba(t+1); MFMA ni=0
    bh = ldsB(bcur, nfb + 0, l); bl = ldsB(bcur, nfb + 1, l);
    stage2<0>(wb, tS, bnxt, wid, l);
    MFMA_PHASE(0);
    __builtin_amdgcn_s_barrier();

    // ---- P1: read b1(t); stage Bb(t+1); MFMA ni=1
    bh = ldsB(bcur, nfb + 2, l); bl = ldsB(bcur, nfb + 3, l);
    stage2<2>(wb, tS, bnxt, wid, l);
    MFMA_PHASE(1);
    __builtin_amdgcn_s_barrier();

    // ---- P2: read b2(t); MFMA ni=2; then retire Aa(t+1), conv mf01, load Aa(t+2)
    bh = ldsB(bcur, nfb + 4, l); bl = ldsB(bcur, nfb + 5, l);
    MFMA_PHASE(2);
    WAITVM(8);                       // retires Aa(t+1)
    conv2<0>(raw, ahn, aln);
    loadA2<0>(xb, tA, raw);
    __builtin_amdgcn_s_barrier();

    // ---- P3: read b3(t); MFMA ni=3; retire Ab(t+1), conv mf23, load Ab(t+2);
    //          retire B(t+1) before trailing barrier (covers next kf's reads)
    bh = ldsB(bcur, nfb + 6, l); bl = ldsB(bcur, nfb + 7, l);
    MFMA_PHASE(3);
    WAITVM(8);                       // retires Ab(t+1)
    conv2<2>(raw, ahn, aln);
    loadA2<2>(xb, tA, raw);
    WAITVM(8);                       // retires Ba(t+1)+Bb(t+1)
    __builtin_amdgcn_s_barrier();
}

// ---------------------------------------------------------------------------
// Kernel 2: split-K GEMM, f16 3-product fp32 emulation, m201-style 4-phase
// schedule per kf: counted vmcnt(8) (T3/T4), setprio (T5), frag-packed B
// (conflict-free ds_read by construction, T2), XCD swizzle (T1).
// ---------------------------------------------------------------------------
__global__ __launch_bounds__(512, 2)
void gemm_kernel(const float* __restrict__ x,
                 const f16* __restrict__ wpk,
                 float* __restrict__ partial) {
    __shared__ __align__(16) char lds[2][32768];   // B only, 64 KiB

    const int tid = threadIdx.x;
    const int l   = tid & 63;
    const int wid = tid >> 6;
    const int bid = blockIdx.x;
    const int swz = (bid & 7) * 32 + (bid >> 3);   // XCD-chunked
    const int ks  = swz >> 6;       // 0..3
    const int mt  = swz & 63;       // 0..63
    const int wr  = wid >> 2;       // 0..1
    const int wc  = wid & 3;        // 0..3

    const float* xb[4];
    #pragma unroll
    for (int mf = 0; mf < 4; ++mf) {
        int row = mt * BM + wr * 64 + mf * 16 + (l & 15);
        xb[mf] = x + (size_t)row * H_DIM + ks * KSL + (l >> 4) * 8;
    }
    const f16* wb = wpk + (size_t)(ks * NSTEP) * 32 * 512;

    f32x4 acc[4][4];
    #pragma unroll
    for (int mi = 0; mi < 4; ++mi)
        #pragma unroll
        for (int ni = 0; ni < 4; ++ni) acc[mi][ni] = (f32x4)0.0f;

    float4 raw[4][2];
    f16x8  ahE[4], alE[4], ahO[4], alO[4];

    // prologue: B(0):4, A(0):8 -> drain -> conv(0)->E -> A(1):8 in flight
    stage2<0>(wb, 0, lds[0], wid, l);
    stage2<2>(wb, 0, lds[0], wid, l);
    loadA2<0>(xb, 0, raw);
    loadA2<2>(xb, 0, raw);
    WAITVM(0);
    conv2<0>(raw, ahE, alE);
    conv2<2>(raw, ahE, alE);
    loadA2<0>(xb, 1, raw);
    loadA2<2>(xb, 1, raw);
    __builtin_amdgcn_s_barrier();

    for (int t = 0; t < NSTEP; t += 2) {
        {
            const int tS = (t + 1 < NSTEP) ? t + 1 : NSTEP - 1;
            const int tA = (t + 2 < NSTEP) ? t + 2 : NSTEP - 1;
            kf_step(tS, tA, lds[0], lds[1], wb, wid, l, wc, xb, raw,
                    ahE, alE, ahO, alO, acc);
        }
        {
            const int tS = (t + 2 < NSTEP) ? t + 2 : NSTEP - 1;
            const int tA = (t + 3 < NSTEP) ? t + 3 : NSTEP - 1;
            kf_step(tS, tA, lds[1], lds[0], wb, wid, l, wc, xb, raw,
                    ahO, alO, ahE, alE, acc);
        }
    }

    float* pbase = partial + ((size_t)ks * B_TOK + (size_t)mt * BM) * E_NUM;
    #pragma unroll
    for (int mi = 0; mi < 4; ++mi)
        #pragma unroll
        for (int ni = 0; ni < 4; ++ni)
            #pragma unroll
            for (int r = 0; r < 4; ++r) {
                int rr = wr * 64 + mi * 16 + (l >> 4) * 4 + r;
                int cc = wc * 64 + ni * 16 + (l & 15);
                pbase[(size_t)rr * E_NUM + cc] = acc[mi][ni][r];
            }
}

// ---------------------------------------------------------------------------
// Kernel 3: fast routing + margin flags.
// ---------------------------------------------------------------------------
__global__ __launch_bounds__(512, 1)
void routing_kernel(const float* __restrict__ partial,
                    const float* __restrict__ bias,
                    float* __restrict__ out,
                    unsigned* __restrict__ flags) {
    const int tid  = threadIdx.x;
    const int l    = tid & 63;
    const int wv   = tid >> 6;
    const int tok0 = blockIdx.x * 32;

    double bj[4];
    #pragma unroll
    for (int q = 0; q < 4; ++q) bj[q] = (double)bias[l + 64 * q];
    const int hf = l >> 5;

    for (int i = 0; i < 4; ++i) {
        const int t = tok0 + wv * 4 + i;
        double lv[4];
        #pragma unroll
        for (int q = 0; q < 4; ++q) {
            double s = 0.0;
            #pragma unroll
            for (int ksl = 0; ksl < NKS; ++ksl)
                s += (double)partial[((size_t)ksl * B_TOK + t) * E_NUM + l + 64 * q];
            lv[q] = s;
        }
        double ma, mg;
        route_token(lv, bj, l, hf, t, out, &ma, &mg);
        if (l == 0 && (ma < TAU || mg < TAU)) {
            unsigned idx = atomicAdd(&flags[0], 1u);
            if (idx < FLAG_CAP) flags[1 + idx] = (unsigned)t;
        }
    }
}

// ---------------------------------------------------------------------------
// Kernel 4: exact fp64 partial dots for flagged tokens.
// ---------------------------------------------------------------------------
__global__ __launch_bounds__(256)
void recompute_dot_kernel(const float* __restrict__ x,
                          const float* __restrict__ W,
                          const unsigned* __restrict__ flags,
                          double* __restrict__ dpart) {
    __shared__ float xs[896];
    unsigned count = flags[0]; if (count > FLAG_CAP) count = FLAG_CAP;
    unsigned nj = count * 8;
    for (unsigned j = blockIdx.x; j < nj; j += gridDim.x) {
        unsigned li = j >> 3, sl = j & 7;
        int t = (int)flags[1 + li];
        const float* xb = x + (size_t)t * H_DIM + sl * 896;
        for (int i = threadIdx.x; i < 224; i += 256)
            *reinterpret_cast<float4*>(&xs[i * 4]) =
                *reinterpret_cast<const float4*>(xb + i * 4);
        __syncthreads();
        const float* wp = W + (size_t)(sl * 896) * E_NUM + threadIdx.x;
        double acc = 0.0;
        #pragma unroll 8
        for (int k = 0; k < 896; ++k)
            acc += (double)xs[k] * (double)wp[(size_t)k * E_NUM];
        dpart[((size_t)li * 8 + sl) * E_NUM + threadIdx.x] = acc;
        __syncthreads();
    }
}

// ---------------------------------------------------------------------------
// Kernel 5: exact routing for flagged tokens (overwrites out).
// ---------------------------------------------------------------------------
__global__ __launch_bounds__(64)
void recompute_route_kernel(const double* __restrict__ dpart,
                            const float* __restrict__ bias,
                            const unsigned* __restrict__ flags,
                            float* __restrict__ out) {
    const int l = threadIdx.x;
    unsigned count = flags[0]; if (count > FLAG_CAP) count = FLAG_CAP;
    double bj[4];
    #pragma unroll
    for (int q = 0; q < 4; ++q) bj[q] = (double)bias[l + 64 * q];
    const int hf = l >> 5;
    for (unsigned li = blockIdx.x; li < count; li += gridDim.x) {
        int t = (int)flags[1 + li];
        double lv[4];
        #pragma unroll
        for (int q = 0; q < 4; ++q) {
            double s = 0.0;
            #pragma unroll
            for (int sl = 0; sl < 8; ++sl)
                s += dpart[((size_t)li * 8 + sl) * E_NUM + l + 64 * q];
            lv[q] = s;
        }
        double ma, mg;
        route_token(lv, bj, l, hf, t, out, &ma, &mg);
    }
}

// ---------------------------------------------------------------------------
// Fallback (round-1 verified fp64 kernel).
// ---------------------------------------------------------------------------
#define TM 32
#define HB 64
#define FNST (H_DIM / HB)

__global__ __launch_bounds__(512, 1)
void moe_gate_fallback(const float* __restrict__ x,
                       const float* __restrict__ W,
                       const float* __restrict__ bias,
                       float* __restrict__ out) {
    __shared__ double xs[TM][HB];
    const int tid  = threadIdx.x;
    const int l    = tid & 63;
    const int wv   = tid >> 6;
    const int tok0 = blockIdx.x * TM;
    const int tl = tid >> 4;
    const int ho = (tid & 15) * 4;

    double acc[4][4];
    #pragma unroll
    for (int i = 0; i < 4; ++i)
        #pragma unroll
        for (int q = 0; q < 4; ++q) acc[i][q] = 0.0;

    const float* xrow = x + (size_t)(tok0 + tl) * H_DIM + ho;
    float4 v = *reinterpret_cast<const float4*>(xrow);

    for (int s = 0; s < FNST; ++s) {
        __syncthreads();
        xs[tl][ho + 0] = (double)v.x;
        xs[tl][ho + 1] = (double)v.y;
        xs[tl][ho + 2] = (double)v.z;
        xs[tl][ho + 3] = (double)v.w;
        __syncthreads();
        const int sn = (s + 1 < FNST) ? s + 1 : s;
        v = *reinterpret_cast<const float4*>(xrow + (size_t)sn * HB);
        const float* wh = W + (size_t)s * HB * E_NUM + l;
        #pragma unroll 4
        for (int h = 0; h < HB; h += 2) {
            float wf0[4], wf1[4];
            #pragma unroll
            for (int q = 0; q < 4; ++q) {
                wf0[q] = wh[(size_t)h       * E_NUM + q * 64];
                wf1[q] = wh[(size_t)(h + 1) * E_NUM + q * 64];
            }
            #pragma unroll
            for (int i = 0; i < 4; ++i) {
                const double2 xv = *reinterpret_cast<const double2*>(&xs[wv * 4 + i][h]);
                #pragma unroll
                for (int q = 0; q < 4; ++q) {
                    acc[i][q] = fma((double)wf0[q], xv.x, acc[i][q]);
                    acc[i][q] = fma((double)wf1[q], xv.y, acc[i][q]);
                }
            }
        }
    }

    double bj[4];
    #pragma unroll
    for (int q = 0; q < 4; ++q) bj[q] = (double)bias[l + 64 * q];
    const int hf = l >> 5;

    for (int i = 0; i < 4; ++i) {
        const int t = tok0 + wv * 4 + i;
        double lv[4];
        #pragma unroll
        for (int q = 0; q < 4; ++q) lv[q] = acc[i][q];
        double ma, mg;
        route_token(lv, bj, l, hf, t, out, &ma, &mg);
    }
}

// ---------------------------------------------------------------------------
extern "C" void kernel_launch(void* const* d_in, const int* in_sizes, int n_in,
                              void* d_out, int out_size, void* d_ws, size_t ws_size,
                              hipStream_t stream) {
    const float* x    = (const float*)d_in[0];
    const float* W    = (const float*)d_in[1];
    const float* bias = (const float*)d_in[2];
    float* out = (float*)d_out;

    const size_t flag_off = 7864320;                  // after 7 MB wpk
    const size_t part_off = 8u * 1024 * 1024;
    const size_t need     = part_off + (size_t)NKS * B_TOK * E_NUM * 4;

    if (ws_size >= need) {
        f16*      wpk     = (f16*)d_ws;
        unsigned* flags   = (unsigned*)((char*)d_ws + flag_off);
        float*    partial = (float*)((char*)d_ws + part_off);
        double*   dpart   = (double*)((char*)d_ws + part_off);   // reused after routing

        convert_w_kernel<<<(H_DIM * E_NUM) / 256, 256, 0, stream>>>(W, wpk, flags);
        gemm_kernel<<<NMT * NKS, 512, 0, stream>>>(x, wpk, partial);
        routing_kernel<<<B_TOK / 32, 512, 0, stream>>>(partial, bias, out, flags);
        recompute_dot_kernel<<<1024, 256, 0, stream>>>(x, W, flags, dpart);
        recompute_route_kernel<<<64, 64, 0, stream>>>(dpart, bias, flags, out);
    } else {
        moe_gate_fallback<<<B_TOK / 32, 512, 0, stream>>>(x, W, bias, out);
    }
}

// Round 8
// 236.565 us; speedup vs baseline: 1.3473x; 1.2509x over previous
//
#include <hip/hip_runtime.h>
#include <math.h>

#define B_TOK 8192
#define H_DIM 7168
#define E_NUM 256
#define NKS   8
#define KSL   (H_DIM / NKS)    // 896
#define BK    32
#define NSTEP (KSL / BK)       // 28
#define BM    128
#define NMT   (B_TOK / BM)     // 64
#define FLAG_CAP 512
#define TAU   2e-6

typedef _Float16 f16;
typedef __attribute__((ext_vector_type(8))) _Float16 f16x8;
typedef __attribute__((ext_vector_type(4))) float    f32x4;

typedef __attribute__((address_space(1))) const void gvoid_t;
typedef __attribute__((address_space(3))) void       lvoid_t;

__device__ inline void gload_lds16(const void* g, void* s) {
    __builtin_amdgcn_global_load_lds((gvoid_t*)g, (lvoid_t*)s, 16, 0, 0);
}

// ---------------------------------------------------------------------------
// Shared routing math (fp64, verified) + decision margins.
// ---------------------------------------------------------------------------
__device__ __forceinline__ void route_token(
    const double* lv, const double* bj, int l, int hf, int t,
    float* __restrict__ out, double* ming_adj, double* ming_grp)
{
    double m = fmax(fmax(lv[0], lv[1]), fmax(lv[2], lv[3]));
    #pragma unroll
    for (int d = 1; d < 64; d <<= 1) m = fmax(m, __shfl_xor(m, d, 64));
    double sc[4], zs = 0.0;
    #pragma unroll
    for (int q = 0; q < 4; ++q) { sc[q] = exp(lv[q] - m); zs += sc[q]; }
    #pragma unroll
    for (int d = 1; d < 64; d <<= 1) zs += __shfl_xor(zs, d, 64);
    double swb[4];
    #pragma unroll
    for (int q = 0; q < 4; ++q) { sc[q] /= zs; swb[q] = sc[q] + bj[q]; }

    double gsq[4];
    #pragma unroll
    for (int q = 0; q < 4; ++q) {
        double a = swb[q], b = -INFINITY;
        #pragma unroll
        for (int d = 1; d <= 16; d <<= 1) {
            double oa = __shfl_xor(a, d, 64), ob = __shfl_xor(b, d, 64);
            double na = fmax(a, oa);
            double nb = fmax(fmin(a, oa), fmax(b, ob));
            a = na; b = nb;
        }
        gsq[q] = a + b;
    }
    double gsv[8];
    #pragma unroll
    for (int q = 0; q < 4; ++q) {
        gsv[2 * q]     = __shfl(gsq[q], 0, 64);
        gsv[2 * q + 1] = __shfl(gsq[q], 32, 64);
    }

    unsigned selmask = 0; double g4 = 0.0, g5 = 0.0;
    #pragma unroll
    for (int k = 0; k < 5; ++k) {
        double best = -INFINITY; int bg = 0;
        #pragma unroll
        for (int g = 0; g < 8; ++g)
            if (gsv[g] > best) { best = gsv[g]; bg = g; }
        if (k < 4) { selmask |= 1u << bg; g4 = best; } else g5 = best;
        #pragma unroll
        for (int g = 0; g < 8; ++g) if (g == bg) gsv[g] = -INFINITY;
    }
    *ming_grp = g4 - g5;

    double mk[4];
    #pragma unroll
    for (int q = 0; q < 4; ++q)
        mk[q] = ((selmask >> (2 * q + hf)) & 1u) ? swb[q] : -INFINITY;

    double wk[8]; int ek[8]; double wsum = 0.0;
    double prev = 0.0, ming = 1e300;
    #pragma unroll
    for (int k = 0; k < 9; ++k) {
        double vbest = mk[0]; int ebest = l;
        #pragma unroll
        for (int q = 1; q < 4; ++q)
            if (mk[q] > vbest) { vbest = mk[q]; ebest = l + 64 * q; }
        #pragma unroll
        for (int d = 1; d < 64; d <<= 1) {
            double ov = __shfl_xor(vbest, d, 64);
            int    oe = __shfl_xor(ebest, d, 64);
            if (ov > vbest || (ov == vbest && oe < ebest)) { vbest = ov; ebest = oe; }
        }
        if (k > 0) ming = fmin(ming, prev - vbest);
        prev = vbest;
        if (k < 8) {
            const int ol = ebest & 63, oq = ebest >> 6;
            if (l == ol) {
                #pragma unroll
                for (int q = 0; q < 4; ++q) if (q == oq) mk[q] = -INFINITY;
            }
            double cand = (oq == 0) ? sc[0] : (oq == 1) ? sc[1] : (oq == 2) ? sc[2] : sc[3];
            double sv = __shfl(cand, ol, 64);
            wk[k] = sv; ek[k] = ebest; wsum += sv;
        }
    }
    *ming_adj = ming;

    if (l == 0) {
        const double inv = 1.0 / wsum;
        #pragma unroll
        for (int k = 0; k < 8; ++k) {
            out[(size_t)t * 8 + k] = (float)((wk[k] * inv + 1e-20) * 2.5);
            out[(size_t)B_TOK * 8 + (size_t)t * 8 + k] = (float)ek[k];
        }
    }
}

// ---------------------------------------------------------------------------
// Kernel 1: pack W into MFMA-B-fragment-ordered f16 hi/lo; reset flag counter.
// frag fg = kf*32 + nf*2 + h; lane l elem j: W[kf*32+(l>>4)*8+j][nf*16+(l&15)]
// ---------------------------------------------------------------------------
__global__ void convert_w_kernel(const float* __restrict__ W,
                                 f16* __restrict__ wpk,
                                 unsigned* __restrict__ flags) {
    if (blockIdx.x == 0 && threadIdx.x == 0) flags[0] = 0;
    int g = blockIdx.x * 256 + threadIdx.x;
    int n = g & 255, k = g >> 8;
    float v = W[(size_t)k * E_NUM + n];
    f16 hi = (f16)v;
    f16 lo = (f16)(v - (float)hi);
    int kf = k >> 5, tq = (k >> 3) & 3, j = k & 7;
    int nf = n >> 4, l = tq * 16 + (n & 15);
    size_t off = ((size_t)(kf * 32 + nf * 2)) * 512 + (size_t)l * 8 + j;
    wpk[off]       = hi;   // h = 0
    wpk[off + 512] = lo;   // h = 1
}

// ---------------------------------------------------------------------------
// GEMM helpers
// ---------------------------------------------------------------------------
__device__ __forceinline__ void stage_B(const f16* __restrict__ wb, int kf,
                                        char* lds, int wid, int l) {
    #pragma unroll
    for (int i = 0; i < 4; ++i) {
        int fi = wid * 4 + i;                        // 0..31 B-fragments
        gload_lds16(wb + ((size_t)kf * 32 + fi) * 512 + (size_t)l * 8,
                    lds + 16384 + fi * 1024);
    }
}

__device__ __forceinline__ void write_A(char* lds, int wid, int l,
                                        float4 a0, float4 a1) {
    float fv[8] = {a0.x, a0.y, a0.z, a0.w, a1.x, a1.y, a1.z, a1.w};
    f16x8 hv, lo;
    #pragma unroll
    for (int j = 0; j < 8; ++j) {
        f16 hh = (f16)fv[j];
        hv[j] = hh;
        lo[j] = (f16)(fv[j] - (float)hh);
    }
    *reinterpret_cast<f16x8*>(&lds[(wid * 2 + 0) * 1024 + l * 16]) = hv;
    *reinterpret_cast<f16x8*>(&lds[(wid * 2 + 1) * 1024 + l * 16]) = lo;
}

__device__ __forceinline__ void compute_step(const char* lds, int wr, int wc,
                                             int l, f32x4 (&acc)[4][4]) {
    const char* Ab = lds;
    const char* Bb = lds + 16384;
    f16x8 af[4][2], bf[4][2];
    #pragma unroll
    for (int mi = 0; mi < 4; ++mi)
        #pragma unroll
        for (int h = 0; h < 2; ++h)
            af[mi][h] = *reinterpret_cast<const f16x8*>(
                Ab + ((wr * 4 + mi) * 2 + h) * 1024 + l * 16);
    #pragma unroll
    for (int ni = 0; ni < 4; ++ni)
        #pragma unroll
        for (int h = 0; h < 2; ++h)
            bf[ni][h] = *reinterpret_cast<const f16x8*>(
                Bb + ((wc * 4 + ni) * 2 + h) * 1024 + l * 16);
    #pragma unroll
    for (int mi = 0; mi < 4; ++mi)
        #pragma unroll
        for (int ni = 0; ni < 4; ++ni) {
            acc[mi][ni] = __builtin_amdgcn_mfma_f32_16x16x32_f16(
                af[mi][0], bf[ni][0], acc[mi][ni], 0, 0, 0);
            acc[mi][ni] = __builtin_amdgcn_mfma_f32_16x16x32_f16(
                af[mi][0], bf[ni][1], acc[mi][ni], 0, 0, 0);
            acc[mi][ni] = __builtin_amdgcn_mfma_f32_16x16x32_f16(
                af[mi][1], bf[ni][0], acc[mi][ni], 0, 0, 0);
        }
}

// ---------------------------------------------------------------------------
// Kernel 2: split-K(8) GEMM, f16 3-product fp32 emulation.
// m97-style single-buffer loop, compiler-managed waits, 2 blocks/CU TLP:
// grid 512, 48 KB LDS, __launch_bounds__(512,4) => 16 waves/CU.
// A raw fp32 loads issued BEFORE compute so their HBM latency hides under
// the MFMA phase; only B gloads (L2) + A ds_writes drain at the stage barrier,
// covered by the co-resident block's compute phase.
// ---------------------------------------------------------------------------
__global__ __launch_bounds__(512, 4)
void gemm_kernel(const float* __restrict__ x,
                 const f16* __restrict__ wpk,
                 float* __restrict__ partial) {
    __shared__ __align__(16) char lds[49152];   // A 16 KB + B 32 KB

    const int tid = threadIdx.x;
    const int l   = tid & 63;
    const int wid = tid >> 6;
    const int bid = blockIdx.x;
    // consecutive bids round-robin XCDs: bid&7 = XCD = ks -> per-XCD L2 holds
    // its 918 KB B slice; each x byte read by exactly one XCD.
    const int ks  = bid & 7;        // 0..7
    const int mt  = bid >> 3;       // 0..63
    const int wr  = wid >> 2;       // 0..1
    const int wc  = wid & 3;        // 0..3

    const int row = mt * BM + wid * 16 + (l & 15);
    const float* xrow = x + (size_t)row * H_DIM + ks * KSL + (l >> 4) * 8;
    const f16* wb = wpk + (size_t)ks * NSTEP * 32 * 512;

    f32x4 acc[4][4];
    #pragma unroll
    for (int mi = 0; mi < 4; ++mi)
        #pragma unroll
        for (int ni = 0; ni < 4; ++ni) acc[mi][ni] = (f32x4)0.0f;

    // prologue: stage tile 0; preload raw A(1)
    float4 a0 = *reinterpret_cast<const float4*>(xrow);
    float4 a1 = *reinterpret_cast<const float4*>(xrow + 4);
    stage_B(wb, 0, lds, wid, l);
    write_A(lds, wid, l, a0, a1);
    a0 = *reinterpret_cast<const float4*>(xrow + BK);
    a1 = *reinterpret_cast<const float4*>(xrow + BK + 4);
    __syncthreads();

    for (int t = 0; t < NSTEP; ++t) {
        // issue raw A(t+2) now — retired during compute, free at stage barrier
        float4 a0n, a1n;
        if (t + 2 < NSTEP) {
            a0n = *reinterpret_cast<const float4*>(xrow + (size_t)(t + 2) * BK);
            a1n = *reinterpret_cast<const float4*>(xrow + (size_t)(t + 2) * BK + 4);
        }
        compute_step(lds, wr, wc, l, acc);
        __syncthreads();                      // all reads of buffer done
        if (t + 1 < NSTEP) {
            stage_B(wb, t + 1, lds, wid, l);  // async into LDS
            write_A(lds, wid, l, a0, a1);     // conv + ds_write
            a0 = a0n; a1 = a1n;
            __syncthreads();                  // stage visible
        }
    }

    float* pbase = partial + ((size_t)ks * B_TOK + (size_t)mt * BM) * E_NUM;
    #pragma unroll
    for (int mi = 0; mi < 4; ++mi)
        #pragma unroll
        for (int ni = 0; ni < 4; ++ni)
            #pragma unroll
            for (int r = 0; r < 4; ++r) {
                int rr = wr * 64 + mi * 16 + (l >> 4) * 4 + r;
                int cc = wc * 64 + ni * 16 + (l & 15);
                pbase[(size_t)rr * E_NUM + cc] = acc[mi][ni][r];
            }
}

// ---------------------------------------------------------------------------
// Kernel 3: fast routing + margin flags.
// ---------------------------------------------------------------------------
__global__ __launch_bounds__(512, 1)
void routing_kernel(const float* __restrict__ partial,
                    const float* __restrict__ bias,
                    float* __restrict__ out,
                    unsigned* __restrict__ flags) {
    const int tid  = threadIdx.x;
    const int l    = tid & 63;
    const int wv   = tid >> 6;
    const int tok0 = blockIdx.x * 32;

    double bj[4];
    #pragma unroll
    for (int q = 0; q < 4; ++q) bj[q] = (double)bias[l + 64 * q];
    const int hf = l >> 5;

    for (int i = 0; i < 4; ++i) {
        const int t = tok0 + wv * 4 + i;
        double lv[4];
        #pragma unroll
        for (int q = 0; q < 4; ++q) {
            double s = 0.0;
            #pragma unroll
            for (int ksl = 0; ksl < NKS; ++ksl)
                s += (double)partial[((size_t)ksl * B_TOK + t) * E_NUM + l + 64 * q];
            lv[q] = s;
        }
        double ma, mg;
        route_token(lv, bj, l, hf, t, out, &ma, &mg);
        if (l == 0 && (ma < TAU || mg < TAU)) {
            unsigned idx = atomicAdd(&flags[0], 1u);
            if (idx < FLAG_CAP) flags[1 + idx] = (unsigned)t;
        }
    }
}

// ---------------------------------------------------------------------------
// Kernel 4: exact fp64 partial dots for flagged tokens.
// ---------------------------------------------------------------------------
__global__ __launch_bounds__(256)
void recompute_dot_kernel(const float* __restrict__ x,
                          const float* __restrict__ W,
                          const unsigned* __restrict__ flags,
                          double* __restrict__ dpart) {
    __shared__ float xs[896];
    unsigned count = flags[0]; if (count > FLAG_CAP) count = FLAG_CAP;
    unsigned nj = count * 8;
    for (unsigned j = blockIdx.x; j < nj; j += gridDim.x) {
        unsigned li = j >> 3, sl = j & 7;
        int t = (int)flags[1 + li];
        const float* xb = x + (size_t)t * H_DIM + sl * 896;
        for (int i = threadIdx.x; i < 224; i += 256)
            *reinterpret_cast<float4*>(&xs[i * 4]) =
                *reinterpret_cast<const float4*>(xb + i * 4);
        __syncthreads();
        const float* wp = W + (size_t)(sl * 896) * E_NUM + threadIdx.x;
        double acc = 0.0;
        #pragma unroll 8
        for (int k = 0; k < 896; ++k)
            acc += (double)xs[k] * (double)wp[(size_t)k * E_NUM];
        dpart[((size_t)li * 8 + sl) * E_NUM + threadIdx.x] = acc;
        __syncthreads();
    }
}

// ---------------------------------------------------------------------------
// Kernel 5: exact routing for flagged tokens (overwrites out).
// ---------------------------------------------------------------------------
__global__ __launch_bounds__(64)
void recompute_route_kernel(const double* __restrict__ dpart,
                            const float* __restrict__ bias,
                            const unsigned* __restrict__ flags,
                            float* __restrict__ out) {
    const int l = threadIdx.x;
    unsigned count = flags[0]; if (count > FLAG_CAP) count = FLAG_CAP;
    double bj[4];
    #pragma unroll
    for (int q = 0; q < 4; ++q) bj[q] = (double)bias[l + 64 * q];
    const int hf = l >> 5;
    for (unsigned li = blockIdx.x; li < count; li += gridDim.x) {
        int t = (int)flags[1 + li];
        double lv[4];
        #pragma unroll
        for (int q = 0; q < 4; ++q) {
            double s = 0.0;
            #pragma unroll
            for (int sl = 0; sl < 8; ++sl)
                s += dpart[((size_t)li * 8 + sl) * E_NUM + l + 64 * q];
            lv[q] = s;
        }
        double ma, mg;
        route_token(lv, bj, l, hf, t, out, &ma, &mg);
    }
}

// ---------------------------------------------------------------------------
// Fallback (round-1 verified fp64 kernel).
// ---------------------------------------------------------------------------
#define TM 32
#define HB 64
#define FNST (H_DIM / HB)

__global__ __launch_bounds__(512, 1)
void moe_gate_fallback(const float* __restrict__ x,
                       const float* __restrict__ W,
                       const float* __restrict__ bias,
                       float* __restrict__ out) {
    __shared__ double xs[TM][HB];
    const int tid  = threadIdx.x;
    const int l    = tid & 63;
    const int wv   = tid >> 6;
    const int tok0 = blockIdx.x * TM;
    const int tl = tid >> 4;
    const int ho = (tid & 15) * 4;

    double acc[4][4];
    #pragma unroll
    for (int i = 0; i < 4; ++i)
        #pragma unroll
        for (int q = 0; q < 4; ++q) acc[i][q] = 0.0;

    const float* xrow = x + (size_t)(tok0 + tl) * H_DIM + ho;
    float4 v = *reinterpret_cast<const float4*>(xrow);

    for (int s = 0; s < FNST; ++s) {
        __syncthreads();
        xs[tl][ho + 0] = (double)v.x;
        xs[tl][ho + 1] = (double)v.y;
        xs[tl][ho + 2] = (double)v.z;
        xs[tl][ho + 3] = (double)v.w;
        __syncthreads();
        const int sn = (s + 1 < FNST) ? s + 1 : s;
        v = *reinterpret_cast<const float4*>(xrow + (size_t)sn * HB);
        const float* wh = W + (size_t)s * HB * E_NUM + l;
        #pragma unroll 4
        for (int h = 0; h < HB; h += 2) {
            float wf0[4], wf1[4];
            #pragma unroll
            for (int q = 0; q < 4; ++q) {
                wf0[q] = wh[(size_t)h       * E_NUM + q * 64];
                wf1[q] = wh[(size_t)(h + 1) * E_NUM + q * 64];
            }
            #pragma unroll
            for (int i = 0; i < 4; ++i) {
                const double2 xv = *reinterpret_cast<const double2*>(&xs[wv * 4 + i][h]);
                #pragma unroll
                for (int q = 0; q < 4; ++q) {
                    acc[i][q] = fma((double)wf0[q], xv.x, acc[i][q]);
                    acc[i][q] = fma((double)wf1[q], xv.y, acc[i][q]);
                }
            }
        }
    }

    double bj[4];
    #pragma unroll
    for (int q = 0; q < 4; ++q) bj[q] = (double)bias[l + 64 * q];
    const int hf = l >> 5;

    for (int i = 0; i < 4; ++i) {
        const int t = tok0 + wv * 4 + i;
        double lv[4];
        #pragma unroll
        for (int q = 0; q < 4; ++q) lv[q] = acc[i][q];
        double ma, mg;
        route_token(lv, bj, l, hf, t, out, &ma, &mg);
    }
}

// ---------------------------------------------------------------------------
extern "C" void kernel_launch(void* const* d_in, const int* in_sizes, int n_in,
                              void* d_out, int out_size, void* d_ws, size_t ws_size,
                              hipStream_t stream) {
    const float* x    = (const float*)d_in[0];
    const float* W    = (const float*)d_in[1];
    const float* bias = (const float*)d_in[2];
    float* out = (float*)d_out;

    const size_t flag_off = 7864320;                  // after 7 MB wpk
    const size_t part_off = 8u * 1024 * 1024;
    const size_t need     = part_off + (size_t)NKS * B_TOK * E_NUM * 4;  // 75 MB

    if (ws_size >= need) {
        f16*      wpk     = (f16*)d_ws;
        unsigned* flags   = (unsigned*)((char*)d_ws + flag_off);
        float*    partial = (float*)((char*)d_ws + part_off);
        double*   dpart   = (double*)((char*)d_ws + part_off);   // reused after routing

        convert_w_kernel<<<(H_DIM * E_NUM) / 256, 256, 0, stream>>>(W, wpk, flags);
        gemm_kernel<<<NMT * NKS, 512, 0, stream>>>(x, wpk, partial);
        routing_kernel<<<B_TOK / 32, 512, 0, stream>>>(partial, bias, out, flags);
        recompute_dot_kernel<<<1024, 256, 0, stream>>>(x, W, flags, dpart);
        recompute_route_kernel<<<64, 64, 0, stream>>>(dpart, bias, flags, out);
    } else {
        moe_gate_fallback<<<B_TOK / 32, 512, 0, stream>>>(x, W, bias, out);
    }
}